// Round 6
// baseline (798.105 us; speedup 1.0000x reference)
//
#include <hip/hip_runtime.h>
#include <cstdint>

#define N_NODES 20000
#define N_EDGES 320000
#define ALPHA 0.2f
#define GAT_EPS 1e-16f
#define MPAD 20096           // 157 * 128
#define SCAN_BLKS 80
#define BT_ROWS 1152         // 9 col-blocks * 128

typedef __attribute__((ext_vector_type(8))) _Float16 half8;
typedef __attribute__((ext_vector_type(4))) float f32x4;

__device__ __forceinline__ float elu1(float x) { return x > 0.f ? x : __expf(x) - 1.f; }

__device__ __forceinline__ void async16(const void* g, void* l) {
    __builtin_amdgcn_global_load_lds(
        (const __attribute__((address_space(1))) unsigned int*)g,
        (__attribute__((address_space(3))) unsigned int*)l, 16, 0, 0);
}

// ---------------- CSR build ----------------
__global__ void hist_kernel(const int* __restrict__ dst, int* __restrict__ counts, int E) {
    int e = blockIdx.x * blockDim.x + threadIdx.x;
    if (e < E) atomicAdd(&counts[dst[e]], 1);
}

__global__ void scan1_kernel(const int* __restrict__ counts, int* __restrict__ excl,
                             int* __restrict__ partial, int N) {
    __shared__ int sh[256];
    int t = threadIdx.x, b = blockIdx.x;
    int i = b * 256 + t;
    int v = (i < N) ? counts[i] : 0;
    sh[t] = v;
    __syncthreads();
    for (int d = 1; d < 256; d <<= 1) {
        int x = (t >= d) ? sh[t - d] : 0;
        __syncthreads();
        sh[t] += x;
        __syncthreads();
    }
    if (i < N) excl[i] = sh[t] - v;
    if (t == 255) partial[b] = sh[255];
}

__global__ void scan2_kernel(int* __restrict__ partial) {
    __shared__ int sh[128];
    int t = threadIdx.x;
    int v = (t < SCAN_BLKS) ? partial[t] : 0;
    sh[t] = v;
    __syncthreads();
    for (int d = 1; d < 128; d <<= 1) {
        int x = (t >= d) ? sh[t - d] : 0;
        __syncthreads();
        sh[t] += x;
        __syncthreads();
    }
    if (t < SCAN_BLKS) partial[t] = sh[t] - v;
}

__global__ void scan3_kernel(const int* __restrict__ excl, const int* __restrict__ partial,
                             int* __restrict__ rowptr, int* __restrict__ cursor, int N, int E) {
    int t = threadIdx.x, b = blockIdx.x;
    int i = b * 256 + t;
    if (i < N) {
        int v = excl[i] + partial[b];
        rowptr[i] = v;
        cursor[i] = v;
    }
    if (i == 0) rowptr[N] = E;
}

__global__ void scatter_kernel(const int* __restrict__ src, const int* __restrict__ dst,
                               int* __restrict__ cursor, int* __restrict__ esrc, int E) {
    int e = blockIdx.x * blockDim.x + threadIdx.x;
    if (e < E) {
        int p = atomicAdd(&cursor[dst[e]], 1);
        esrc[p] = src[e];
    }
}

// ---------------- packs ----------------
__global__ void pack_x16(const float* __restrict__ x, _Float16* __restrict__ A) {
    int idx = blockIdx.x * 256 + threadIdx.x;   // MPAD*64
    int r = idx >> 6, c = idx & 63;
    float v = (r < N_NODES && c < 50) ? x[r * 50 + c] : 0.f;
    A[idx] = (_Float16)v;
}

__global__ void pack_bt1(const float* __restrict__ W, _Float16* __restrict__ Bt) {
    int idx = blockIdx.x * 256 + threadIdx.x;   // 1024*64
    int c = idx >> 6, k = idx & 63;
    int h = c >> 8, f = c & 255;
    float v = (k < 50) ? W[((size_t)h * 50 + k) * 256 + f] : 0.f;
    Bt[idx] = (_Float16)v;
}

__global__ void pack_bt16(const float* __restrict__ W, _Float16* __restrict__ Bt,
                          int F, int Ctot) {
    int c = blockIdx.y;
    int k = blockIdx.x * blockDim.x + threadIdx.x;
    float v = 0.f;
    if (c < Ctot) {
        int h = c / F, f = c - h * F;
        v = W[(size_t)h * 1024 * F + (size_t)k * F + f];
    }
    Bt[(size_t)c * 1024 + k] = (_Float16)v;
}

// W~ columns appended at BT rows [Nfeat, Nfeat+2H):  BT[Nfeat+j][k] = sum_f W[h,k,f]*a[h,(j>=H?F:0)+f]
__global__ void wtilde_kernel(const float* __restrict__ W, const float* __restrict__ a,
                              _Float16* __restrict__ BT, int Kreal, int Kdim,
                              int F, int H, int Nfeat) {
    int idx = blockIdx.x * 256 + threadIdx.x;
    int j = idx / Kdim, k = idx - j * Kdim;
    if (j >= 2 * H) return;
    int h = j < H ? j : j - H;
    int ao = j < H ? 0 : F;
    float s = 0.f;
    if (k < Kreal) {
        const float* wp = W + ((size_t)h * Kreal + k) * F;
        const float* ap = a + (size_t)h * 2 * F + ao;
        for (int f = 0; f < F; f++) s += wp[f] * ap[f];
    }
    BT[(size_t)(Nfeat + j) * Kdim + k] = (_Float16)s;
}

// ---------------- fp16 MFMA GEMM, BK=64, XOR-swizzled LDS, fused score cols ----------------
// C[M][Nfeat](fp16, ld) = A @ BT^T ; cols [Nfeat, Nfeat+12) -> SPRE fp32 [j][N_NODES]
__global__ __launch_bounds__(256) void gemm_f16(const _Float16* __restrict__ A,
                                                const _Float16* __restrict__ BT,
                                                _Float16* __restrict__ C,
                                                float* __restrict__ SPRE,
                                                int M, int Nfeat, int ld, int Kdim) {
    __shared__ __align__(16) _Float16 sA[128 * 64];
    __shared__ __align__(16) _Float16 sB[128 * 64];
    int t = threadIdx.x;
    int row0 = blockIdx.y * 128, col0 = blockIdx.x * 128;
    int lane = t & 63, wave = t >> 6;
    int wm = wave >> 1, wn = wave & 1;
    int fr = lane & 15;
    int fq = lane >> 4;

    const _Float16* gA = A + (size_t)row0 * Kdim;
    const _Float16* gB = BT + (size_t)col0 * Kdim;

    int sR[4], sgl[4];
#pragma unroll
    for (int i = 0; i < 4; i++) {
        int m = i * 256 + t;
        sR[i] = m >> 3;
        sgl[i] = (m & 7) ^ (sR[i] & 7);
    }

    f32x4 acc[4][4] = {};

    for (int k0 = 0; k0 < Kdim; k0 += 64) {
        __syncthreads();
#pragma unroll
        for (int i = 0; i < 4; i++) {
            const _Float16* pa = gA + (size_t)sR[i] * Kdim + k0 + sgl[i] * 8;
            const _Float16* pb = gB + (size_t)sR[i] * Kdim + k0 + sgl[i] * 8;
            async16(pa, sA + (i * 256 + t) * 8);
            async16(pb, sB + (i * 256 + t) * 8);
        }
        __syncthreads();
#pragma unroll
        for (int ks = 0; ks < 2; ks++) {
            half8 af[4], bf[4];
#pragma unroll
            for (int mt = 0; mt < 4; mt++) {
                int R = wm * 64 + mt * 16 + fr;
                int gp = (ks * 4 + fq) ^ (R & 7);
                af[mt] = *(const half8*)(sA + R * 64 + gp * 8);
            }
#pragma unroll
            for (int nt = 0; nt < 4; nt++) {
                int R = wn * 64 + nt * 16 + fr;
                int gp = (ks * 4 + fq) ^ (R & 7);
                bf[nt] = *(const half8*)(sB + R * 64 + gp * 8);
            }
#pragma unroll
            for (int mt = 0; mt < 4; mt++)
#pragma unroll
                for (int nt = 0; nt < 4; nt++)
                    acc[mt][nt] = __builtin_amdgcn_mfma_f32_16x16x32_f16(af[mt], bf[nt], acc[mt][nt], 0, 0, 0);
        }
    }

    int rbase = row0 + wm * 64 + ((lane >> 4) << 2);
    int cbase = col0 + wn * 64 + (lane & 15);
#pragma unroll
    for (int mt = 0; mt < 4; mt++)
#pragma unroll
        for (int nt = 0; nt < 4; nt++) {
            int gc = cbase + nt * 16;
            if (gc < Nfeat) {
#pragma unroll
                for (int r = 0; r < 4; r++) {
                    int gr = rbase + mt * 16 + r;
                    if (gr < M) C[(size_t)gr * ld + gc] = (_Float16)acc[mt][nt][r];
                }
            } else if (gc < Nfeat + 12) {
                int j = gc - Nfeat;
#pragma unroll
                for (int r = 0; r < 4; r++) {
                    int gr = rbase + mt * 16 + r;
                    if (gr < M) SPRE[(size_t)j * N_NODES + gr] = acc[mt][nt][r];
                }
            }
        }
}

// ---------------- per-edge attention weights (CSR order) ----------------
__global__ __launch_bounds__(64) void att_kernel(const int* __restrict__ rowptr,
                                                 const int* __restrict__ esrc,
                                                 const float* __restrict__ SS,
                                                 const float* __restrict__ SD,
                                                 float* __restrict__ ATT, int N, int H) {
    int n = blockIdx.x, lane = threadIdx.x;
    int start = rowptr[n], end = rowptr[n + 1];
    for (int h = 0; h < H; h++) {
        const float* ss = SS + (size_t)h * N;
        float sd = SD[(size_t)h * N + n];
        float* att = ATT + (size_t)h * N_EDGES;
        float m = -INFINITY;
        for (int e = start + lane; e < end; e += 64) {
            float sc = ss[esrc[e]] + sd;
            sc = sc > 0.f ? sc : ALPHA * sc;
            m = fmaxf(m, sc);
        }
#pragma unroll
        for (int off = 32; off; off >>= 1) m = fmaxf(m, __shfl_down(m, off));
        m = __shfl(m, 0);
        float psum = 0.f;
        for (int e = start + lane; e < end; e += 64) {
            float sc = ss[esrc[e]] + sd;
            sc = sc > 0.f ? sc : ALPHA * sc;
            float p = __expf(sc - m);
            psum += p;
            att[e] = p;
        }
#pragma unroll
        for (int off = 32; off; off >>= 1) psum += __shfl_down(psum, off);
        psum = __shfl(psum, 0);
        float inv = 1.f / (psum + GAT_EPS);
        for (int e = start + lane; e < end; e += 64) att[e] *= inv;
    }
}

// ---------------- aggregate Fout=256 layers: 64-feature XCD tiles, q-split ----------------
// grid N*8; block id = n*8 + t; t -> head t>>1, 64-col chunk (t&1); launch q picks 128-half.
// Per-XCD hot slice = 20000 x 64 x 2B = 2.5 MB -> L2-resident.
__global__ __launch_bounds__(64) void agg256_kernel(const _Float16* __restrict__ WH16,
                                                    const int* __restrict__ rowptr,
                                                    const int* __restrict__ esrc,
                                                    const float* __restrict__ ATT,
                                                    _Float16* __restrict__ X16,
                                                    int use_skip, int q) {
    int id = blockIdx.x;
    int t = id & 7, n = id >> 3;
    int h = t >> 1, sub = t & 1;
    int lane = threadIdx.x;
    int base = h * 256 + q * 128 + sub * 64 + lane;
    int start = rowptr[n], end = rowptr[n + 1];
    const float* ap = ATT + (size_t)h * N_EDGES;
    const _Float16* W = WH16 + base;
    float acc = 0.f;
    int e = start;
    for (; e + 8 <= end; e += 8) {
        int i0 = esrc[e],     i1 = esrc[e + 1], i2 = esrc[e + 2], i3 = esrc[e + 3];
        int i4 = esrc[e + 4], i5 = esrc[e + 5], i6 = esrc[e + 6], i7 = esrc[e + 7];
        float w0 = (float)W[(size_t)i0 * 1024], w1 = (float)W[(size_t)i1 * 1024];
        float w2 = (float)W[(size_t)i2 * 1024], w3 = (float)W[(size_t)i3 * 1024];
        float w4 = (float)W[(size_t)i4 * 1024], w5 = (float)W[(size_t)i5 * 1024];
        float w6 = (float)W[(size_t)i6 * 1024], w7 = (float)W[(size_t)i7 * 1024];
        acc += ap[e] * w0 + ap[e + 1] * w1 + ap[e + 2] * w2 + ap[e + 3] * w3
             + ap[e + 4] * w4 + ap[e + 5] * w5 + ap[e + 6] * w6 + ap[e + 7] * w7;
    }
    for (; e < end; e++) acc += ap[e] * (float)W[(size_t)esrc[e] * 1024];
    size_t o = (size_t)n * 1024 + base;
    float v = use_skip ? elu1(elu1(acc) + (float)X16[o]) : elu1(elu1(acc));
    X16[o] = (_Float16)v;
}

// ---------------- layer 3: 12 (head, 64/57-chunk) tiles, atomicAdd into out ----------------
__global__ __launch_bounds__(64) void agg726_kernel(const _Float16* __restrict__ WH16,
                                                    const int* __restrict__ rowptr,
                                                    const int* __restrict__ esrc,
                                                    const float* __restrict__ ATT,
                                                    float* __restrict__ out) {
    int id = blockIdx.x;
    int n = id / 12;
    int t = id - n * 12;
    int h = t >> 1, half = t & 1;
    int lane = threadIdx.x;
    int len = half ? 57 : 64;
    if (lane >= len) return;
    int f = half * 64 + lane;
    const _Float16* W = WH16 + h * 121 + f;     // row stride 768
    const float* ap = ATT + (size_t)h * N_EDGES;
    int start = rowptr[n], end = rowptr[n + 1];
    float acc = 0.f;
    int e = start;
    for (; e + 8 <= end; e += 8) {
        int i0 = esrc[e],     i1 = esrc[e + 1], i2 = esrc[e + 2], i3 = esrc[e + 3];
        int i4 = esrc[e + 4], i5 = esrc[e + 5], i6 = esrc[e + 6], i7 = esrc[e + 7];
        float w0 = (float)W[(size_t)i0 * 768], w1 = (float)W[(size_t)i1 * 768];
        float w2 = (float)W[(size_t)i2 * 768], w3 = (float)W[(size_t)i3 * 768];
        float w4 = (float)W[(size_t)i4 * 768], w5 = (float)W[(size_t)i5 * 768];
        float w6 = (float)W[(size_t)i6 * 768], w7 = (float)W[(size_t)i7 * 768];
        acc += ap[e] * w0 + ap[e + 1] * w1 + ap[e + 2] * w2 + ap[e + 3] * w3
             + ap[e + 4] * w4 + ap[e + 5] * w5 + ap[e + 6] * w6 + ap[e + 7] * w7;
    }
    for (; e < end; e++) acc += ap[e] * (float)W[(size_t)esrc[e] * 768];
    atomicAdd(&out[(size_t)n * 121 + f], acc);
}

__global__ void sigmoid_kernel(float* __restrict__ out, int total) {
    int i = blockIdx.x * 256 + threadIdx.x;
    if (i < total) out[i] = 1.f / (1.f + __expf(-out[i] * (1.f / 6.f)));
}

extern "C" void kernel_launch(void* const* d_in, const int* in_sizes, int n_in,
                              void* d_out, int out_size, void* d_ws, size_t ws_size,
                              hipStream_t stream) {
    const float* x  = (const float*)d_in[0];
    const int*   ei = (const int*)d_in[1];
    const float* W1 = (const float*)d_in[2];
    const float* a1 = (const float*)d_in[3];
    const float* W2 = (const float*)d_in[4];
    const float* a2 = (const float*)d_in[5];
    const float* W3 = (const float*)d_in[6];
    const float* a3 = (const float*)d_in[7];
    float* out = (float*)d_out;
    const int N = N_NODES, E = N_EDGES;
    const int* src = ei;
    const int* dst = ei + E;

    char* ws = (char*)d_ws;
    size_t off = 0;
    auto alloc = [&](size_t b) { size_t o = off; off += (b + 255) & ~(size_t)255; return o; };
    _Float16* X16  = (_Float16*)(ws + alloc((size_t)MPAD * 1024 * 2)); // x1 then x2
    _Float16* WH16 = (_Float16*)(ws + alloc((size_t)MPAD * 1024 * 2)); // per-layer Wh
    _Float16* BT16 = (_Float16*)(ws + alloc((size_t)BT_ROWS * 1024 * 2));
    _Float16* A1   = (_Float16*)(ws + alloc((size_t)MPAD * 64 * 2));
    _Float16* BT1  = (_Float16*)(ws + alloc((size_t)BT_ROWS * 64 * 2));
    float* SPRE   = (float*)(ws + alloc((size_t)12 * N * 4));
    float* ATT    = (float*)(ws + alloc((size_t)6 * E * 4));
    int*   rowptr = (int*)(ws + alloc((size_t)(N + 1) * 4));
    int*   cursor = (int*)(ws + alloc((size_t)N * 4));
    int*   counts = (int*)(ws + alloc((size_t)N * 4));
    int*   excl   = (int*)(ws + alloc((size_t)N * 4));
    int*   partial= (int*)(ws + alloc((size_t)SCAN_BLKS * 4));
    int*   esrc   = (int*)(ws + alloc((size_t)E * 4));

    // CSR by dst
    hipMemsetAsync(counts, 0, (size_t)N * 4, stream);
    hist_kernel<<<(E + 255) / 256, 256, 0, stream>>>(dst, counts, E);
    scan1_kernel<<<SCAN_BLKS, 256, 0, stream>>>(counts, excl, partial, N);
    scan2_kernel<<<1, 128, 0, stream>>>(partial);
    scan3_kernel<<<SCAN_BLKS, 256, 0, stream>>>(excl, partial, rowptr, cursor, N, E);
    scatter_kernel<<<(E + 255) / 256, 256, 0, stream>>>(src, dst, cursor, esrc, E);
    hipMemsetAsync(X16 + (size_t)N * 1024, 0, (size_t)(MPAD - N) * 1024 * 2, stream);

    // ---- layer 1: 50 -> 4x256 concat ----
    pack_x16<<<MPAD * 64 / 256, 256, 0, stream>>>(x, A1);
    pack_bt1<<<1024 * 64 / 256, 256, 0, stream>>>(W1, BT1);
    wtilde_kernel<<<(12 * 64 + 255) / 256, 256, 0, stream>>>(W1, a1, BT1, 50, 64, 256, 4, 1024);
    gemm_f16<<<dim3(9, 157), 256, 0, stream>>>(A1, BT1, WH16, SPRE, N, 1024, 1024, 64);
    att_kernel<<<N, 64, 0, stream>>>(rowptr, esrc, SPRE, SPRE + 4 * N, ATT, N, 4);
    agg256_kernel<<<N * 8, 64, 0, stream>>>(WH16, rowptr, esrc, ATT, X16, 0, 0);
    agg256_kernel<<<N * 8, 64, 0, stream>>>(WH16, rowptr, esrc, ATT, X16, 0, 1);

    // ---- layer 2: 1024 -> 4x256 concat + skip ----
    pack_bt16<<<dim3(4, 1024), 256, 0, stream>>>(W2, BT16, 256, 1024);
    wtilde_kernel<<<(12 * 1024 + 255) / 256, 256, 0, stream>>>(W2, a2, BT16, 1024, 1024, 256, 4, 1024);
    gemm_f16<<<dim3(9, 157), 256, 0, stream>>>(X16, BT16, WH16, SPRE, N, 1024, 1024, 1024);
    att_kernel<<<N, 64, 0, stream>>>(rowptr, esrc, SPRE, SPRE + 4 * N, ATT, N, 4);
    agg256_kernel<<<N * 8, 64, 0, stream>>>(WH16, rowptr, esrc, ATT, X16, 1, 0);
    agg256_kernel<<<N * 8, 64, 0, stream>>>(WH16, rowptr, esrc, ATT, X16, 1, 1);

    // ---- layer 3: 1024 -> 6x121, mean over heads, sigmoid ----
    pack_bt16<<<dim3(4, 768), 256, 0, stream>>>(W3, BT16, 121, 726);
    wtilde_kernel<<<(12 * 1024 + 255) / 256, 256, 0, stream>>>(W3, a3, BT16, 1024, 1024, 121, 6, 726);
    gemm_f16<<<dim3(6, 157), 256, 0, stream>>>(X16, BT16, WH16, SPRE, N, 726, 768, 1024);
    att_kernel<<<N, 64, 0, stream>>>(rowptr, esrc, SPRE, SPRE + 6 * N, ATT, N, 6);
    hipMemsetAsync(out, 0, (size_t)N * 121 * 4, stream);
    agg726_kernel<<<N * 12, 64, 0, stream>>>(WH16, rowptr, esrc, ATT, out);
    sigmoid_kernel<<<(N * 121 + 255) / 256, 256, 0, stream>>>(out, N * 121);
}